// Round 8
// baseline (895.089 us; speedup 1.0000x reference)
//
#include <hip/hip_runtime.h>
#include <hip/hip_cooperative_groups.h>
#include <math.h>

namespace cg = cooperative_groups;

#define N_NODES 20000
#define N_EDGESC 320000
#define ET (N_EDGESC + N_NODES)   // 340000 incl. self-loops
#define F_IN 128
#define H1 512
#define H2 256
#define N_CLS 40
#define NEG_SLOPE 0.2f
#define LDT 40   // padded LDS stride (bf16) per 32-wide k tile
#define LSO 66   // epilogue repack stride (bf16)

typedef __attribute__((ext_vector_type(8))) short short8;
typedef __attribute__((ext_vector_type(4))) float floatx4;

__device__ __forceinline__ unsigned short f2bf(float x) {
    unsigned u = __float_as_uint(x);
    unsigned r = (u + 0x7fffu + ((u >> 16) & 1u)) >> 16;  // RNE
    return (unsigned short)r;
}
__device__ __forceinline__ float bflo(unsigned v) { return __uint_as_float(v << 16); }
__device__ __forceinline__ float bfhi(unsigned v) { return __uint_as_float(v & 0xffff0000u); }
__device__ __forceinline__ float leaky(float e) { return (e > 0.f) ? e : e * NEG_SLOPE; }

struct Params {
    const float* x; const int* ei;
    const float *W1, *a1s, *a1d, *b1;
    const float *W2, *a2s, *a2d, *b2;
    const float *W3, *a3s, *a3d, *b3;
    float* out;
    int *deg, *writeptr, *rowptr, *csr_src;
    float *alph, *wab;
    unsigned short *xb, *w1t, *w2t, *w3t, *zb, *y1, *h2;
    float* h3;
};

// phase block counts
#define NCT (F_IN * H1 + H1 * H2 + H2 * N_CLS)  // 206848
#define PB_CASTX 2500
#define PB_CASTT ((NCT + 255) / 256)             // 808
#define PB_WA 224
#define PB_ZERO ((N_NODES + 255) / 256)          // 79
#define PB_TOT (PB_CASTX + PB_CASTT + PB_WA + PB_ZERO)
#define CB_CNT ((ET + 255) / 256)                // 1329
#define NODEB ((N_NODES + 3) / 4)                // 5000
#define MT64 ((N_NODES + 63) / 64)               // 313

// ---------------- gemv body: als[i]=in[i,:].wvs, ald[i]=in[i,:].wvd --------
template <int DIN, bool IN_BF16>
__device__ __forceinline__ void gemv2_body(int node, int lane, const void* in,
                                           const float* wvs, const float* wvd,
                                           float* als, float* ald) {
    constexpr int C = DIN / 64;
    float ss = 0.f, sd = 0.f;
    if constexpr (IN_BF16) {
        const unsigned short* r = (const unsigned short*)in + (size_t)node * DIN + lane * C;
        float f[C];
        if constexpr (C == 8) {
            uint4 v = *(const uint4*)r;
            f[0] = bflo(v.x); f[1] = bfhi(v.x); f[2] = bflo(v.y); f[3] = bfhi(v.y);
            f[4] = bflo(v.z); f[5] = bfhi(v.z); f[6] = bflo(v.w); f[7] = bfhi(v.w);
        } else {
            uint2 v = *(const uint2*)r;
            f[0] = bflo(v.x); f[1] = bfhi(v.x); f[2] = bflo(v.y); f[3] = bfhi(v.y);
        }
        #pragma unroll
        for (int c = 0; c < C; ++c) {
            ss += f[c] * wvs[lane * C + c];
            sd += f[c] * wvd[lane * C + c];
        }
    } else {
        const float* r = (const float*)in + (size_t)node * DIN + lane * 2;
        float2 v = *(const float2*)r;
        ss = v.x * wvs[lane * 2] + v.y * wvs[lane * 2 + 1];
        sd = v.x * wvd[lane * 2] + v.y * wvd[lane * 2 + 1];
    }
    #pragma unroll
    for (int off = 32; off; off >>= 1) {
        ss += __shfl_xor(ss, off);
        sd += __shfl_xor(sd, off);
    }
    if (lane == 0) { als[node] = ss; ald[node] = sd; }
}

// ---------------- P0: cast x, W^T casts, wa GEMVs, zero deg ----------------
__device__ void prep_vb(int bid, const Params& p) {
    int t = threadIdx.x;
    if (bid < PB_CASTX) {
        int i = (bid * 256 + t) * 4;
        float4 v = *(const float4*)(p.x + i);
        ushort4 o = { f2bf(v.x), f2bf(v.y), f2bf(v.z), f2bf(v.w) };
        *(ushort4*)(p.xb + i) = o;
    } else if (bid < PB_CASTX + PB_CASTT) {
        int i = (bid - PB_CASTX) * 256 + t;
        if (i < F_IN * H1) {
            int k = i >> 9, n = i & 511;
            p.w1t[n * F_IN + k] = f2bf(p.W1[i]);
        } else if (i < F_IN * H1 + H1 * H2) {
            int j = i - F_IN * H1;
            int k = j >> 8, n = j & 255;
            p.w2t[n * H1 + k] = f2bf(p.W2[j]);
        } else if (i < NCT) {
            int j = i - (F_IN * H1 + H1 * H2);
            int k = j / N_CLS, n = j - k * N_CLS;
            p.w3t[n * H2 + k] = f2bf(p.W3[j]);
        }
    } else if (bid < PB_CASTX + PB_CASTT + PB_WA) {
        int lane = t & 63;
        int row = (bid - PB_CASTX - PB_CASTT) * 4 + (t >> 6);  // 0..895
        const float *W, *vs, *vd;
        float *os, *od;
        int N, k;
        if (row < 128)      { k = row;       W = p.W1; vs = p.a1s; vd = p.a1d; os = p.wab;        od = p.wab + 128;  N = H1; }
        else if (row < 640) { k = row - 128; W = p.W2; vs = p.a2s; vd = p.a2d; os = p.wab + 256;  od = p.wab + 768;  N = H2; }
        else                { k = row - 640; W = p.W3; vs = p.a3s; vd = p.a3d; os = p.wab + 1280; od = p.wab + 1536; N = N_CLS; }
        const float* r = W + (size_t)k * N;
        float ss = 0.f, sd = 0.f;
        for (int n = lane; n < N; n += 64) {
            float v = r[n];
            ss += v * vs[n];
            sd += v * vd[n];
        }
        #pragma unroll
        for (int off = 32; off; off >>= 1) {
            ss += __shfl_xor(ss, off);
            sd += __shfl_xor(sd, off);
        }
        if (lane == 0) { os[k] = ss; od[k] = sd; }
    } else {
        int i = (bid - PB_CASTX - PB_CASTT - PB_WA) * 256 + t;
        if (i < N_NODES) p.deg[i] = 0;
    }
}

// ---------------- P2: single-block scan (256 threads) ----------------------
__device__ void scan256(const Params& p, int* sums) {
    int t = threadIdx.x;
    const int per = (N_NODES + 255) / 256;  // 79
    int base = t * per;
    int local = 0;
    for (int i = 0; i < per; ++i) {
        int idx = base + i;
        if (idx < N_NODES) local += p.deg[idx];
    }
    sums[t] = local;
    __syncthreads();
    for (int off = 1; off < 256; off <<= 1) {
        int add = (t >= off) ? sums[t - off] : 0;
        __syncthreads();
        sums[t] += add;
        __syncthreads();
    }
    int run = sums[t] - local;
    for (int i = 0; i < per; ++i) {
        int idx = base + i;
        if (idx < N_NODES) {
            p.rowptr[idx] = run;
            p.writeptr[idx] = run;
            run += p.deg[idx];
        }
    }
    if (t == 255) p.rowptr[N_NODES] = sums[255];
}

// ---------------- P3: CSR fill ---------------------------------------------
__device__ void fill_vb(int bid, const Params& p) {
    int e = bid * 256 + threadIdx.x;
    if (e >= ET) return;
    int s, d;
    if (e < N_EDGESC) { s = p.ei[e]; d = p.ei[N_EDGESC + e]; }
    else { s = d = e - N_EDGESC; }
    int pos = atomicAdd(&p.writeptr[d], 1);
    p.csr_src[pos] = s;
}

// ---------------- MFMA GEMM tile, MT=64, BK=32, reg double-buffer ----------
template <int NT, bool BIASRELU, bool OUT_BF16>
__device__ void gemm64_vb(int vb, const unsigned short* __restrict__ A,
                          const unsigned short* __restrict__ Bt,
                          void* __restrict__ Cp, const float* __restrict__ bias,
                          int M, int K, int N,
                          unsigned short* As, unsigned short* Bs, unsigned short* Ls) {
    int t = threadIdx.x;
    int w = t >> 6, lane = t & 63;
    int quad = lane >> 4, l16 = lane & 15;
    int bm = (vb / NT) * 64, bn = (vb % NT) * 64;
    int ar = t >> 2, ak = (t & 3) * 8;
    int gm = bm + ar, gn = bn + ar;

    floatx4 acc[4];
    #pragma unroll
    for (int j = 0; j < 4; ++j) acc[j] = (floatx4){0.f, 0.f, 0.f, 0.f};

    uint4 pa = {0,0,0,0}, pb = {0,0,0,0};
    if (gm < M) pa = *(const uint4*)(A + (size_t)gm * K + ak);
    if (gn < N) pb = *(const uint4*)(Bt + (size_t)gn * K + ak);

    for (int k0 = 0; k0 < K; k0 += 32) {
        *(uint4*)(&As[ar * LDT + ak]) = pa;
        *(uint4*)(&Bs[ar * LDT + ak]) = pb;
        __syncthreads();

        int kn = k0 + 32;
        if (kn < K) {
            pa = (gm < M) ? *(const uint4*)(A + (size_t)gm * K + kn + ak) : (uint4){0,0,0,0};
            pb = (gn < N) ? *(const uint4*)(Bt + (size_t)gn * K + kn + ak) : (uint4){0,0,0,0};
        }

        short8 a = *(short8*)(&As[(w * 16 + l16) * LDT + quad * 8]);
        short8 b[4];
        #pragma unroll
        for (int ni = 0; ni < 4; ++ni)
            b[ni] = *(short8*)(&Bs[(ni * 16 + l16) * LDT + quad * 8]);
        #pragma unroll
        for (int ni = 0; ni < 4; ++ni)
            acc[ni] = __builtin_amdgcn_mfma_f32_16x16x32_bf16(a, b[ni], acc[ni], 0, 0, 0);
        __syncthreads();
    }

    if constexpr (OUT_BF16) {
        #pragma unroll
        for (int ni = 0; ni < 4; ++ni) {
            int col = bn + ni * 16 + l16;
            #pragma unroll
            for (int r = 0; r < 4; ++r) {
                float v = acc[ni][r];
                if constexpr (BIASRELU) v = fmaxf(v + bias[col], 0.f);
                Ls[(w * 16 + quad * 4 + r) * LSO + ni * 16 + l16] = f2bf(v);
            }
        }
        __syncthreads();
        #pragma unroll
        for (int i = 0; i < 2; ++i) {
            int idx = t + i * 256;
            int lrow = idx >> 3, c8 = (idx & 7) * 8;
            int grow = bm + lrow;
            if (grow < M)
                *(uint4*)((unsigned short*)Cp + (size_t)grow * N + bn + c8) =
                    *(uint4*)(&Ls[lrow * LSO + c8]);
        }
        __syncthreads();
    } else {
        #pragma unroll
        for (int r = 0; r < 4; ++r) {
            int row = bm + w * 16 + quad * 4 + r;
            if (row >= M) continue;
            #pragma unroll
            for (int ni = 0; ni < 4; ++ni) {
                int col = bn + ni * 16 + l16;
                if (col < N) ((float*)Cp)[(size_t)row * N + col] = acc[ni][r];
            }
        }
    }
}

// ---------------- softmax-attention aggregation for one node ---------------
template <int DOUT, bool BIAS, bool RELU, bool LSM, bool IN_BF16, bool OUT_BF16>
__device__ void agg_node(int node, int lane, const void* __restrict__ h,
                         const float* __restrict__ as, const float* __restrict__ ad,
                         const int* __restrict__ rowptr, const int* __restrict__ csr_src,
                         const float* __restrict__ bias, void* __restrict__ outp) {
    constexpr int C = (DOUT + 63) / 64;
    int beg = rowptr[node], end = rowptr[node + 1];
    float adi = ad[node];

    int k0 = beg + lane;
    bool has0 = k0 < end;
    int sj = has0 ? csr_src[k0] : 0;
    float ej = -INFINITY;
    if (has0) ej = leaky(as[sj] + adi);

    float m = ej;
    for (int k = k0 + 64; k < end; k += 64) m = fmaxf(m, leaky(as[csr_src[k]] + adi));
    #pragma unroll
    for (int off = 32; off; off >>= 1) m = fmaxf(m, __shfl_xor(m, off));

    float den = has0 ? expf(ej - m) : 0.f;
    for (int k = k0 + 64; k < end; k += 64) den += expf(leaky(as[csr_src[k]] + adi) - m);
    #pragma unroll
    for (int off = 32; off; off >>= 1) den += __shfl_xor(den, off);
    float invden = 1.f / den;

    float wgt = has0 ? expf(ej - m) * invden : 0.f;

    float acc[C];
    #pragma unroll
    for (int c = 0; c < C; ++c) acc[c] = 0.f;

    auto fetch = [&](int s, float* f) {
        if constexpr (IN_BF16) {
            const unsigned short* hr = (const unsigned short*)h + (size_t)s * DOUT + lane * C;
            if constexpr (C == 8) {
                uint4 v = *(const uint4*)hr;
                f[0] = bflo(v.x); f[1] = bfhi(v.x); f[2] = bflo(v.y); f[3] = bfhi(v.y);
                f[4] = bflo(v.z); f[5] = bfhi(v.z); f[6] = bflo(v.w); f[7] = bfhi(v.w);
            } else if constexpr (C == 4) {
                uint2 v = *(const uint2*)hr;
                f[0] = bflo(v.x); f[1] = bfhi(v.x); f[2] = bflo(v.y); f[3] = bfhi(v.y);
            } else {
                unsigned v = *(const unsigned*)hr;
                f[0] = bflo(v); f[1] = bfhi(v);
            }
        } else {
            if (lane < DOUT) f[0] = ((const float*)h)[(size_t)s * DOUT + lane];
            else f[0] = 0.f;
        }
    };

    int cnt0 = min(64, end - beg);
    int j = 0;
    for (; j + 7 < cnt0; j += 8) {
        int s[8]; float a[8]; float f[8][C];
        #pragma unroll
        for (int u = 0; u < 8; ++u) { s[u] = __shfl(sj, j + u); a[u] = __shfl(wgt, j + u); }
        #pragma unroll
        for (int u = 0; u < 8; ++u) fetch(s[u], f[u]);
        #pragma unroll
        for (int u = 0; u < 8; ++u)
            #pragma unroll
            for (int c = 0; c < C; ++c) acc[c] += a[u] * f[u][c];
    }
    for (; j < cnt0; ++j) {
        int s0 = __shfl(sj, j);
        float a0 = __shfl(wgt, j);
        float f0[C];
        fetch(s0, f0);
        #pragma unroll
        for (int c = 0; c < C; ++c) acc[c] += a0 * f0[c];
    }
    for (int base = beg + 64; base < end; base += 64) {  // rare: degree > 64
        int cnt = min(64, end - base);
        int sx = 0; float wx = 0.f;
        if (lane < cnt) {
            sx = csr_src[base + lane];
            wx = expf(leaky(as[sx] + adi) - m) * invden;
        }
        for (int jj = 0; jj < cnt; ++jj) {
            int s0 = __shfl(sx, jj);
            float a0 = __shfl(wx, jj);
            float f0[C];
            fetch(s0, f0);
            #pragma unroll
            for (int c = 0; c < C; ++c) acc[c] += a0 * f0[c];
        }
    }

    if constexpr (!LSM) {
        #pragma unroll
        for (int c = 0; c < C; ++c) {
            int col = lane * C + c;
            if (DOUT % 64 == 0 || col < DOUT) {
                float v = acc[c];
                if constexpr (BIAS) v += bias[col];
                if constexpr (RELU) v = fmaxf(v, 0.f);
                if constexpr (OUT_BF16)
                    ((unsigned short*)outp)[(size_t)node * DOUT + col] = f2bf(v);
                else
                    ((float*)outp)[(size_t)node * DOUT + col] = v;
            }
        }
    } else {
        float v = (lane < DOUT) ? (acc[0] + bias[lane]) : -INFINITY;
        float mm = v;
        #pragma unroll
        for (int off = 32; off; off >>= 1) mm = fmaxf(mm, __shfl_xor(mm, off));
        float ex = (lane < DOUT) ? expf(v - mm) : 0.f;
        float Z = ex;
        #pragma unroll
        for (int off = 32; off; off >>= 1) Z += __shfl_xor(Z, off);
        if (lane < DOUT) ((float*)outp)[(size_t)node * DOUT + lane] = v - mm - logf(Z);
    }
}

// ---------------- the whole net as one cooperative kernel ------------------
__global__ __launch_bounds__(256, 4) void mega(Params p) {
    cg::grid_group g = cg::this_grid();
    const int nb = gridDim.x, bx = blockIdx.x;
    const int t = threadIdx.x, w = t >> 6, lane = t & 63;
    __shared__ unsigned short As[64 * LDT];
    __shared__ unsigned short Bs[64 * LDT];
    __shared__ unsigned short Ls[64 * LSO];

    float* als1 = p.alph + 0 * N_NODES; float* ald1 = p.alph + 1 * N_NODES;
    float* als2 = p.alph + 2 * N_NODES; float* ald2 = p.alph + 3 * N_NODES;
    float* als3 = p.alph + 4 * N_NODES; float* ald3 = p.alph + 5 * N_NODES;

    // P0: prep
    for (int vb = bx; vb < PB_TOT; vb += nb) prep_vb(vb, p);
    g.sync();
    // P1: count_deg + gemv-L1
    for (int vb = bx; vb < CB_CNT + NODEB; vb += nb) {
        if (vb < CB_CNT) {
            int e = vb * 256 + t;
            if (e < ET) {
                int d = (e < N_EDGESC) ? p.ei[N_EDGESC + e] : (e - N_EDGESC);
                atomicAdd(&p.deg[d], 1);
            }
        } else {
            int node = (vb - CB_CNT) * 4 + w;
            if (node < N_NODES)
                gemv2_body<F_IN, false>(node, lane, p.x, p.wab, p.wab + 128, als1, ald1);
        }
    }
    g.sync();
    // P2: scan (block 0)
    if (bx == 0) scan256(p, (int*)As);
    g.sync();
    // P3: CSR fill
    for (int vb = bx; vb < CB_CNT; vb += nb) fill_vb(vb, p);
    g.sync();
    // P4: layer-1 aggregation in input space (zb = agg(xb))
    for (int vb = bx; vb < NODEB; vb += nb) {
        int node = vb * 4 + w;
        if (node < N_NODES)
            agg_node<F_IN, false, false, false, true, true>(
                node, lane, p.xb, als1, ald1, p.rowptr, p.csr_src, nullptr, p.zb);
    }
    g.sync();
    // P5: gemm1: y1 = relu(zb @ W1 + b1)
    for (int vb = bx; vb < MT64 * 8; vb += nb)
        gemm64_vb<8, true, true>(vb, p.zb, p.w1t, p.y1, p.b1, N_NODES, F_IN, H1, As, Bs, Ls);
    g.sync();
    // P6: gemm2 (h2 = y1 @ W2) + gemv-L2
    for (int vb = bx; vb < MT64 * 4 + NODEB; vb += nb) {
        if (vb < MT64 * 4)
            gemm64_vb<4, false, true>(vb, p.y1, p.w2t, p.h2, nullptr, N_NODES, H1, H2, As, Bs, Ls);
        else {
            int node = (vb - MT64 * 4) * 4 + w;
            if (node < N_NODES)
                gemv2_body<H1, true>(node, lane, p.y1, p.wab + 256, p.wab + 768, als2, ald2);
        }
    }
    g.sync();
    // P7: layer-2 aggregation: y2(=y1) = relu(agg(h2) + b2)
    for (int vb = bx; vb < NODEB; vb += nb) {
        int node = vb * 4 + w;
        if (node < N_NODES)
            agg_node<H2, true, true, false, true, true>(
                node, lane, p.h2, als2, ald2, p.rowptr, p.csr_src, p.b2, p.y1);
    }
    g.sync();
    // P8: gemm3 (h3 = y2 @ W3, fp32) + gemv-L3
    for (int vb = bx; vb < MT64 + NODEB; vb += nb) {
        if (vb < MT64)
            gemm64_vb<1, false, false>(vb, p.y1, p.w3t, p.h3, nullptr, N_NODES, H2, N_CLS, As, Bs, Ls);
        else {
            int node = (vb - MT64) * 4 + w;
            if (node < N_NODES)
                gemv2_body<H2, true>(node, lane, p.y1, p.wab + 1280, p.wab + 1536, als3, ald3);
        }
    }
    g.sync();
    // P9: layer-3 aggregation + bias + log_softmax
    for (int vb = bx; vb < NODEB; vb += nb) {
        int node = vb * 4 + w;
        if (node < N_NODES)
            agg_node<N_CLS, true, false, true, false, false>(
                node, lane, p.h3, als3, ald3, p.rowptr, p.csr_src, p.b3, p.out);
    }
}

// ---------------- launch ----------------

extern "C" void kernel_launch(void* const* d_in, const int* in_sizes, int n_in,
                              void* d_out, int out_size, void* d_ws, size_t ws_size,
                              hipStream_t stream) {
    char* ws = (char*)d_ws;
    size_t off = 0;
    auto alloc = [&](size_t bytes) {
        void* p = ws + off;
        off = (off + bytes + 255) & ~(size_t)255;
        return p;
    };
    Params p;
    p.x   = (const float*)d_in[0];
    p.ei  = (const int*)d_in[1];
    p.W1  = (const float*)d_in[2];  p.a1s = (const float*)d_in[3];
    p.a1d = (const float*)d_in[4];  p.b1  = (const float*)d_in[5];
    p.W2  = (const float*)d_in[6];  p.a2s = (const float*)d_in[7];
    p.a2d = (const float*)d_in[8];  p.b2  = (const float*)d_in[9];
    p.W3  = (const float*)d_in[10]; p.a3s = (const float*)d_in[11];
    p.a3d = (const float*)d_in[12]; p.b3  = (const float*)d_in[13];
    p.out = (float*)d_out;

    p.deg      = (int*)alloc(N_NODES * 4);
    p.writeptr = (int*)alloc(N_NODES * 4);
    p.rowptr   = (int*)alloc((N_NODES + 1) * 4);
    p.csr_src  = (int*)alloc((size_t)ET * 4);
    p.alph     = (float*)alloc((size_t)6 * N_NODES * 4);
    p.wab      = (float*)alloc(1792 * 4);
    p.xb       = (unsigned short*)alloc((size_t)N_NODES * F_IN * 2);
    p.w1t      = (unsigned short*)alloc((size_t)H1 * F_IN * 2);
    p.w2t      = (unsigned short*)alloc((size_t)H2 * H1 * 2);
    p.w3t      = (unsigned short*)alloc((size_t)N_CLS * H2 * 2);
    p.zb       = (unsigned short*)alloc((size_t)N_NODES * F_IN * 2);
    p.y1       = (unsigned short*)alloc((size_t)N_NODES * H1 * 2);
    p.h2       = (unsigned short*)alloc((size_t)N_NODES * H2 * 2);
    p.h3       = (float*)alloc((size_t)N_NODES * N_CLS * 4);
    (void)alloc(128 * 1024);  // slack

    int maxb = 0;
    hipOccupancyMaxActiveBlocksPerMultiprocessor(&maxb, mega, 256, 0);
    if (maxb < 1) maxb = 1;
    long long grid = (long long)maxb * 256;  // 256 CUs on MI355X
    if (grid > 2048) grid = 2048;

    void* args[] = { &p };
    hipLaunchCooperativeKernel(mega, dim3((unsigned)grid), dim3(256), args, 0, stream);
}

// Round 9
// 267.376 us; speedup vs baseline: 3.3477x; 3.3477x over previous
//
#include <hip/hip_runtime.h>
#include <math.h>

#define N_NODES 20000
#define N_EDGESC 320000
#define ET (N_EDGESC + N_NODES)   // 340000 incl. self-loops
#define F_IN 128
#define H1 512
#define H2 256
#define N_CLS 40
#define NEG_SLOPE 0.2f

typedef __attribute__((ext_vector_type(8))) short short8;
typedef __attribute__((ext_vector_type(4))) float floatx4;

__device__ __forceinline__ unsigned short f2bf(float x) {
    unsigned u = __float_as_uint(x);
    unsigned r = (u + 0x7fffu + ((u >> 16) & 1u)) >> 16;  // RNE
    return (unsigned short)r;
}
__device__ __forceinline__ float bflo(unsigned v) { return __uint_as_float(v << 16); }
__device__ __forceinline__ float bfhi(unsigned v) { return __uint_as_float(v & 0xffff0000u); }
__device__ __forceinline__ float leaky(float e) { return (e > 0.f) ? e : e * NEG_SLOPE; }

// ---------------- gemv body: als[i]=in[i,:].wvs, ald[i]=in[i,:].wvd --------
template <int DIN, bool IN_BF16>
__device__ __forceinline__ void gemv2_body(int node, int lane, const void* __restrict__ in,
                                           const float* __restrict__ wvs,
                                           const float* __restrict__ wvd,
                                           float* __restrict__ als, float* __restrict__ ald) {
    constexpr int C = DIN / 64;
    float ss = 0.f, sd = 0.f;
    if constexpr (IN_BF16) {
        const unsigned short* r = (const unsigned short*)in + (size_t)node * DIN + lane * C;
        float f[C];
        if constexpr (C == 8) {
            uint4 v = *(const uint4*)r;
            f[0] = bflo(v.x); f[1] = bfhi(v.x); f[2] = bflo(v.y); f[3] = bfhi(v.y);
            f[4] = bflo(v.z); f[5] = bfhi(v.z); f[6] = bflo(v.w); f[7] = bfhi(v.w);
        } else {
            uint2 v = *(const uint2*)r;
            f[0] = bflo(v.x); f[1] = bfhi(v.x); f[2] = bflo(v.y); f[3] = bfhi(v.y);
        }
        #pragma unroll
        for (int c = 0; c < C; ++c) {
            ss += f[c] * wvs[lane * C + c];
            sd += f[c] * wvd[lane * C + c];
        }
    } else {
        const float* r = (const float*)in + (size_t)node * DIN + lane * 2;
        float2 v = *(const float2*)r;
        ss = v.x * wvs[lane * 2] + v.y * wvs[lane * 2 + 1];
        sd = v.x * wvd[lane * 2] + v.y * wvd[lane * 2 + 1];
    }
    #pragma unroll
    for (int off = 32; off; off >>= 1) {
        ss += __shfl_xor(ss, off);
        sd += __shfl_xor(sd, off);
    }
    if (lane == 0) { als[node] = ss; ald[node] = sd; }
}

// ---------------- prep: cast x, W^T casts, wa GEMVs, zero deg+alph ---------
#define NCT (F_IN * H1 + H1 * H2 + H2 * N_CLS)  // 206848
#define PB_CASTX 2500
#define PB_CASTT ((NCT + 255) / 256)             // 808
#define PB_WA 224
#define PB_ZERO ((3 * N_NODES + 255) / 256)      // 235: deg + als2/ald2

__global__ __launch_bounds__(256) void prep_kernel(
        const float* __restrict__ x, unsigned short* __restrict__ xb,
        const float* __restrict__ W1, unsigned short* __restrict__ w1t,
        const float* __restrict__ a1s, const float* __restrict__ a1d,
        const float* __restrict__ W2, unsigned short* __restrict__ w2t,
        const float* __restrict__ a2s, const float* __restrict__ a2d,
        const float* __restrict__ W3, unsigned short* __restrict__ w3t,
        const float* __restrict__ a3s, const float* __restrict__ a3d,
        float* __restrict__ wab, int* __restrict__ deg, float* __restrict__ alph) {
    int bid = blockIdx.x, t = threadIdx.x;
    if (bid < PB_CASTX) {
        int i = (bid * 256 + t) * 4;
        float4 v = *(const float4*)(x + i);
        ushort4 o = { f2bf(v.x), f2bf(v.y), f2bf(v.z), f2bf(v.w) };
        *(ushort4*)(xb + i) = o;
    } else if (bid < PB_CASTX + PB_CASTT) {
        int i = (bid - PB_CASTX) * 256 + t;
        if (i < F_IN * H1) {
            int k = i >> 9, n = i & 511;
            w1t[n * F_IN + k] = f2bf(W1[i]);
        } else if (i < F_IN * H1 + H1 * H2) {
            int j = i - F_IN * H1;
            int k = j >> 8, n = j & 255;
            w2t[n * H1 + k] = f2bf(W2[j]);
        } else if (i < NCT) {
            int j = i - (F_IN * H1 + H1 * H2);
            int k = j / N_CLS, n = j - k * N_CLS;
            w3t[n * H2 + k] = f2bf(W3[j]);
        }
    } else if (bid < PB_CASTX + PB_CASTT + PB_WA) {
        int lane = t & 63;
        int row = (bid - PB_CASTX - PB_CASTT) * 4 + (t >> 6);  // 0..895
        const float *W, *vs, *vd;
        float *os, *od;
        int N, k;
        if (row < 128)      { k = row;       W = W1; vs = a1s; vd = a1d; os = wab;        od = wab + 128;  N = H1; }
        else if (row < 640) { k = row - 128; W = W2; vs = a2s; vd = a2d; os = wab + 256;  od = wab + 768;  N = H2; }
        else                { k = row - 640; W = W3; vs = a3s; vd = a3d; os = wab + 1280; od = wab + 1536; N = N_CLS; }
        const float* r = W + (size_t)k * N;
        float ss = 0.f, sd = 0.f;
        for (int n = lane; n < N; n += 64) {
            float v = r[n];
            ss += v * vs[n];
            sd += v * vd[n];
        }
        #pragma unroll
        for (int off = 32; off; off >>= 1) {
            ss += __shfl_xor(ss, off);
            sd += __shfl_xor(sd, off);
        }
        if (lane == 0) { os[k] = ss; od[k] = sd; }
    } else {
        int i = (bid - PB_CASTX - PB_CASTT - PB_WA) * 256 + t;
        if (i < N_NODES) deg[i] = 0;
        else if (i < 3 * N_NODES) alph[2 * N_NODES + (i - N_NODES)] = 0.f;  // als2/ald2
    }
}

// ---------------- count_deg + gemv-L1 --------------------------------------
#define CB_CNT ((ET + 255) / 256)  // 1329

__global__ __launch_bounds__(256) void count_gemv1_kernel(
        const int* __restrict__ ei, int* __restrict__ deg,
        const float* __restrict__ x, const float* __restrict__ wab,
        float* __restrict__ als1, float* __restrict__ ald1) {
    int bid = blockIdx.x, t = threadIdx.x;
    if (bid < CB_CNT) {
        int e = bid * 256 + t;
        if (e < ET) {
            int d = (e < N_EDGESC) ? ei[N_EDGESC + e] : (e - N_EDGESC);
            atomicAdd(&deg[d], 1);
        }
    } else {
        int node = (bid - CB_CNT) * 4 + (t >> 6);
        if (node < N_NODES)
            gemv2_body<F_IN, false>(node, t & 63, x, wab, wab + 128, als1, ald1);
    }
}

__global__ __launch_bounds__(1024) void scan_kernel(const int* __restrict__ deg,
                                                    int* __restrict__ rowptr,
                                                    int* __restrict__ writeptr) {
    __shared__ int sums[1024];
    int t = threadIdx.x;
    const int per = (N_NODES + 1023) / 1024;  // 20
    int base = t * per;
    int local = 0;
    for (int i = 0; i < per; ++i) {
        int idx = base + i;
        if (idx < N_NODES) local += deg[idx];
    }
    sums[t] = local;
    __syncthreads();
    for (int off = 1; off < 1024; off <<= 1) {
        int add = (t >= off) ? sums[t - off] : 0;
        __syncthreads();
        sums[t] += add;
        __syncthreads();
    }
    int run = sums[t] - local;
    for (int i = 0; i < per; ++i) {
        int idx = base + i;
        if (idx < N_NODES) {
            rowptr[idx] = run;
            writeptr[idx] = run;
            run += deg[idx];
        }
    }
    if (t == 1023) rowptr[N_NODES] = sums[1023];
}

__global__ void fill_kernel(const int* __restrict__ ei, int* __restrict__ writeptr,
                            int* __restrict__ csr_src) {
    int e = blockIdx.x * blockDim.x + threadIdx.x;
    if (e >= ET) return;
    int s, d;
    if (e < N_EDGESC) { s = ei[e]; d = ei[N_EDGESC + e]; }
    else { s = d = e - N_EDGESC; }
    int pos = atomicAdd(&writeptr[d], 1);
    csr_src[pos] = s;
}

// ---------------- MFMA GEMM (1D grid) + optional fused alpha epilogue ------
// C(MxN) = A(MxK bf16 rm) * Bt(NxK bf16 rm). ALPHA: o_s[row] += sum_col
// C[row,col]*av_s[col] (post-activation values), via l16 shuffle + atomicAdd.
#define LDT 40   // padded LDS stride (bf16) per 32-wide k tile
#define LSO 66   // epilogue repack stride (bf16)

template <int MT, int NT, bool BIASRELU, bool OUT_BF16, bool ALPHA>
__global__ __launch_bounds__(256) void gemm_fused(
        const unsigned short* __restrict__ A, const unsigned short* __restrict__ Bt,
        void* __restrict__ Cp, const float* __restrict__ bias,
        int M, int K, int N,
        const float* __restrict__ av_s, const float* __restrict__ av_d,
        float* __restrict__ o_s, float* __restrict__ o_d) {
    constexpr int MI = MT / 64;
    __shared__ unsigned short As[MT * LDT];
    __shared__ unsigned short Bs[64 * LDT];
    __shared__ unsigned short Ls[64 * LSO];
    int bid = blockIdx.x, t = threadIdx.x;
    int w = t >> 6, lane = t & 63;
    int quad = lane >> 4, l16 = lane & 15;
    int bm = (bid / NT) * MT, bn = (bid % NT) * 64;

    int ar0 = t >> 2;
    int ak = (t & 3) * 8;

    floatx4 acc[MI][4];
    #pragma unroll
    for (int i = 0; i < MI; ++i)
        #pragma unroll
        for (int j = 0; j < 4; ++j) acc[i][j] = (floatx4){0.f, 0.f, 0.f, 0.f};

    uint4 pa0 = {0,0,0,0}, pa1 = {0,0,0,0}, pb = {0,0,0,0};
    {
        int gm0 = bm + ar0, gn = bn + ar0;
        if (gm0 < M) pa0 = *(const uint4*)(A + (size_t)gm0 * K + ak);
        if constexpr (MI == 2) {
            int gm1 = bm + 64 + ar0;
            if (gm1 < M) pa1 = *(const uint4*)(A + (size_t)gm1 * K + ak);
        }
        if (gn < N) pb = *(const uint4*)(Bt + (size_t)gn * K + ak);
    }

    for (int k0 = 0; k0 < K; k0 += 32) {
        *(uint4*)(&As[ar0 * LDT + ak]) = pa0;
        if constexpr (MI == 2) *(uint4*)(&As[(64 + ar0) * LDT + ak]) = pa1;
        *(uint4*)(&Bs[ar0 * LDT + ak]) = pb;
        __syncthreads();

        int kn = k0 + 32;
        if (kn < K) {
            int gm0 = bm + ar0, gn = bn + ar0;
            pa0 = (gm0 < M) ? *(const uint4*)(A + (size_t)gm0 * K + kn + ak) : (uint4){0,0,0,0};
            if constexpr (MI == 2) {
                int gm1 = bm + 64 + ar0;
                pa1 = (gm1 < M) ? *(const uint4*)(A + (size_t)gm1 * K + kn + ak) : (uint4){0,0,0,0};
            }
            pb = (gn < N) ? *(const uint4*)(Bt + (size_t)gn * K + kn + ak) : (uint4){0,0,0,0};
        }

        short8 a[MI], b[4];
        #pragma unroll
        for (int mi = 0; mi < MI; ++mi)
            a[mi] = *(short8*)(&As[(w * (MT / 4) + mi * 16 + l16) * LDT + quad * 8]);
        #pragma unroll
        for (int ni = 0; ni < 4; ++ni)
            b[ni] = *(short8*)(&Bs[(ni * 16 + l16) * LDT + quad * 8]);
        #pragma unroll
        for (int mi = 0; mi < MI; ++mi)
            #pragma unroll
            for (int ni = 0; ni < 4; ++ni)
                acc[mi][ni] = __builtin_amdgcn_mfma_f32_16x16x32_bf16(a[mi], b[ni], acc[mi][ni], 0, 0, 0);
        __syncthreads();
    }

    if constexpr (OUT_BF16) {
        #pragma unroll
        for (int mi = 0; mi < MI; ++mi) {
            float ps[4] = {0.f, 0.f, 0.f, 0.f}, pd[4] = {0.f, 0.f, 0.f, 0.f};
            #pragma unroll
            for (int ni = 0; ni < 4; ++ni) {
                int col = bn + ni * 16 + l16;
                float avs = 0.f, avd = 0.f;
                if constexpr (ALPHA) { avs = av_s[col]; avd = av_d[col]; }
                #pragma unroll
                for (int r = 0; r < 4; ++r) {
                    float v = acc[mi][ni][r];
                    if constexpr (BIASRELU) v = fmaxf(v + bias[col], 0.f);
                    if constexpr (ALPHA) { ps[r] += v * avs; pd[r] += v * avd; }
                    Ls[(w * 16 + quad * 4 + r) * LSO + ni * 16 + l16] = f2bf(v);
                }
            }
            if constexpr (ALPHA) {
                #pragma unroll
                for (int r = 0; r < 4; ++r) {
                    #pragma unroll
                    for (int msk = 1; msk <= 8; msk <<= 1) {
                        ps[r] += __shfl_xor(ps[r], msk);
                        pd[r] += __shfl_xor(pd[r], msk);
                    }
                }
                if (l16 == 0) {
                    #pragma unroll
                    for (int r = 0; r < 4; ++r) {
                        int row = bm + w * (MT / 4) + mi * 16 + quad * 4 + r;
                        if (row < M) {
                            atomicAdd(&o_s[row], ps[r]);
                            atomicAdd(&o_d[row], pd[r]);
                        }
                    }
                }
            }
            __syncthreads();
            #pragma unroll
            for (int i = 0; i < 2; ++i) {
                int idx = t + i * 256;
                int lrow = idx >> 3, c8 = (idx & 7) * 8;
                int grow = bm + (lrow >> 4) * (MT / 4) + mi * 16 + (lrow & 15);
                if (grow < M)
                    *(uint4*)((unsigned short*)Cp + (size_t)grow * N + bn + c8) =
                        *(uint4*)(&Ls[lrow * LSO + c8]);
            }
            __syncthreads();
        }
    } else {
        #pragma unroll
        for (int mi = 0; mi < MI; ++mi) {
            #pragma unroll
            for (int r = 0; r < 4; ++r) {
                int row = bm + w * (MT / 4) + mi * 16 + quad * 4 + r;
                if (row >= M) continue;
                #pragma unroll
                for (int ni = 0; ni < 4; ++ni) {
                    int col = bn + ni * 16 + l16;
                    if (col < N) ((float*)Cp)[(size_t)row * N + col] = acc[mi][ni][r];
                }
            }
        }
    }
}

// ---------------- softmax-attention aggregation ----------------------------
// ALPHA3: compute o3s[node]=out_row . wv3s, o3d likewise (fused next-layer alphas)
template <int DOUT, bool BIAS, bool RELU, bool LSM, bool IN_BF16, bool OUT_BF16, bool ALPHA3>
__global__ __launch_bounds__(256) void agg_kernel(const void* __restrict__ h,
                                                  const float* __restrict__ as,
                                                  const float* __restrict__ ad,
                                                  const int* __restrict__ rowptr,
                                                  const int* __restrict__ csr_src,
                                                  const float* __restrict__ bias,
                                                  void* __restrict__ outp,
                                                  const float* __restrict__ wv3s,
                                                  const float* __restrict__ wv3d,
                                                  float* __restrict__ o3s,
                                                  float* __restrict__ o3d) {
    constexpr int C = (DOUT + 63) / 64;
    int wave = threadIdx.x >> 6, lane = threadIdx.x & 63;
    int node = blockIdx.x * 4 + wave;
    if (node >= N_NODES) return;
    int beg = rowptr[node], end = rowptr[node + 1];
    float adi = ad[node];

    int k0 = beg + lane;
    bool has0 = k0 < end;
    int sj = has0 ? csr_src[k0] : 0;
    float ej = -INFINITY;
    if (has0) ej = leaky(as[sj] + adi);

    float m = ej;
    for (int k = k0 + 64; k < end; k += 64) m = fmaxf(m, leaky(as[csr_src[k]] + adi));
    #pragma unroll
    for (int off = 32; off; off >>= 1) m = fmaxf(m, __shfl_xor(m, off));

    float den = has0 ? expf(ej - m) : 0.f;
    for (int k = k0 + 64; k < end; k += 64) den += expf(leaky(as[csr_src[k]] + adi) - m);
    #pragma unroll
    for (int off = 32; off; off >>= 1) den += __shfl_xor(den, off);
    float invden = 1.f / den;

    float wgt = has0 ? expf(ej - m) * invden : 0.f;

    float acc[C];
    #pragma unroll
    for (int c = 0; c < C; ++c) acc[c] = 0.f;

    auto fetch = [&](int s, float* f) {
        if constexpr (IN_BF16) {
            const unsigned short* hr = (const unsigned short*)h + (size_t)s * DOUT + lane * C;
            if constexpr (C == 8) {
                uint4 v = *(const uint4*)hr;
                f[0] = bflo(v.x); f[1] = bfhi(v.x); f[2] = bflo(v.y); f[3] = bfhi(v.y);
                f[4] = bflo(v.z); f[5] = bfhi(v.z); f[6] = bflo(v.w); f[7] = bfhi(v.w);
            } else if constexpr (C == 4) {
                uint2 v = *(const uint2*)hr;
                f[0] = bflo(v.x); f[1] = bfhi(v.x); f[2] = bflo(v.y); f[3] = bfhi(v.y);
            } else {
                unsigned v = *(const unsigned*)hr;
                f[0] = bflo(v); f[1] = bfhi(v);
            }
        } else {
            if (lane < DOUT) f[0] = ((const float*)h)[(size_t)s * DOUT + lane];
            else f[0] = 0.f;
        }
    };

    int cnt0 = min(64, end - beg);
    int j = 0;
    for (; j + 7 < cnt0; j += 8) {
        int s[8]; float a[8]; float f[8][C];
        #pragma unroll
        for (int u = 0; u < 8; ++u) { s[u] = __shfl(sj, j + u); a[u] = __shfl(wgt, j + u); }
        #pragma unroll
        for (int u = 0; u < 8; ++u) fetch(s[u], f[u]);
        #pragma unroll
        for (int u = 0; u < 8; ++u)
            #pragma unroll
            for (int c = 0; c < C; ++c) acc[c] += a[u] * f[u][c];
    }
    for (; j < cnt0; ++j) {
        int s0 = __shfl(sj, j);
        float a0 = __shfl(wgt, j);
        float f0[C];
        fetch(s0, f0);
        #pragma unroll
        for (int c = 0; c < C; ++c) acc[c] += a0 * f0[c];
    }
    for (int base = beg + 64; base < end; base += 64) {  // rare: degree > 64
        int cnt = min(64, end - base);
        int sx = 0; float wx = 0.f;
        if (lane < cnt) {
            sx = csr_src[base + lane];
            wx = expf(leaky(as[sx] + adi) - m) * invden;
        }
        for (int jj = 0; jj < cnt; ++jj) {
            int s0 = __shfl(sx, jj);
            float a0 = __shfl(wx, jj);
            float f0[C];
            fetch(s0, f0);
            #pragma unroll
            for (int c = 0; c < C; ++c) acc[c] += a0 * f0[c];
        }
    }

    if constexpr (!LSM) {
        float ps = 0.f, pd = 0.f;
        #pragma unroll
        for (int c = 0; c < C; ++c) {
            int col = lane * C + c;
            if (DOUT % 64 == 0 || col < DOUT) {
                float v = acc[c];
                if constexpr (BIAS) v += bias[col];
                if constexpr (RELU) v = fmaxf(v, 0.f);
                if constexpr (ALPHA3) { ps += v * wv3s[col]; pd += v * wv3d[col]; }
                if constexpr (OUT_BF16)
                    ((unsigned short*)outp)[(size_t)node * DOUT + col] = f2bf(v);
                else
                    ((float*)outp)[(size_t)node * DOUT + col] = v;
            }
        }
        if constexpr (ALPHA3) {
            #pragma unroll
            for (int off = 32; off; off >>= 1) {
                ps += __shfl_xor(ps, off);
                pd += __shfl_xor(pd, off);
            }
            if (lane == 0) { o3s[node] = ps; o3d[node] = pd; }
        }
    } else {
        float v = (lane < DOUT) ? (acc[0] + bias[lane]) : -INFINITY;
        float mm = v;
        #pragma unroll
        for (int off = 32; off; off >>= 1) mm = fmaxf(mm, __shfl_xor(mm, off));
        float ex = (lane < DOUT) ? expf(v - mm) : 0.f;
        float Z = ex;
        #pragma unroll
        for (int off = 32; off; off >>= 1) Z += __shfl_xor(Z, off);
        if (lane < DOUT) ((float*)outp)[(size_t)node * DOUT + lane] = v - mm - logf(Z);
    }
}

// ---------------- launch ----------------

extern "C" void kernel_launch(void* const* d_in, const int* in_sizes, int n_in,
                              void* d_out, int out_size, void* d_ws, size_t ws_size,
                              hipStream_t stream) {
    const float* x   = (const float*)d_in[0];
    const int*   ei  = (const int*)d_in[1];
    const float* W1  = (const float*)d_in[2];
    const float* a1s = (const float*)d_in[3];
    const float* a1d = (const float*)d_in[4];
    const float* b1  = (const float*)d_in[5];
    const float* W2  = (const float*)d_in[6];
    const float* a2s = (const float*)d_in[7];
    const float* a2d = (const float*)d_in[8];
    const float* b2  = (const float*)d_in[9];
    const float* W3  = (const float*)d_in[10];
    const float* a3s = (const float*)d_in[11];
    const float* a3d = (const float*)d_in[12];
    const float* b3  = (const float*)d_in[13];
    float* out = (float*)d_out;

    char* ws = (char*)d_ws;
    size_t off = 0;
    auto alloc = [&](size_t bytes) {
        void* p = ws + off;
        off = (off + bytes + 255) & ~(size_t)255;
        return p;
    };
    int*            deg      = (int*)alloc(N_NODES * 4);
    int*            writeptr = (int*)alloc(N_NODES * 4);
    int*            rowptr   = (int*)alloc((N_NODES + 1) * 4);
    int*            csr_src  = (int*)alloc((size_t)ET * 4);
    float*          alph     = (float*)alloc((size_t)6 * N_NODES * 4);
    float*          wab      = (float*)alloc(1792 * 4);
    unsigned short* xb       = (unsigned short*)alloc((size_t)N_NODES * F_IN * 2);
    unsigned short* w1t      = (unsigned short*)alloc((size_t)H1 * F_IN * 2);
    unsigned short* w2t      = (unsigned short*)alloc((size_t)H2 * H1 * 2);
    unsigned short* w3t      = (unsigned short*)alloc((size_t)N_CLS * H2 * 2);
    unsigned short* zb       = (unsigned short*)alloc((size_t)N_NODES * F_IN * 2);  // agg(x)
    unsigned short* y1       = (unsigned short*)alloc((size_t)N_NODES * H1 * 2);    // L1 out / L2-agg out (aliased)
    unsigned short* h2       = (unsigned short*)alloc((size_t)N_NODES * H2 * 2);
    float*          h3       = (float*)alloc((size_t)N_NODES * N_CLS * 4);
    (void)alloc(128 * 1024);  // slack

    unsigned short* y2 = y1;  // y1 fully consumed before y2 is produced

    float* als1 = alph + 0 * N_NODES; float* ald1 = alph + 1 * N_NODES;
    float* als2 = alph + 2 * N_NODES; float* ald2 = alph + 3 * N_NODES;
    float* als3 = alph + 4 * N_NODES; float* ald3 = alph + 5 * N_NODES;

    dim3 blk(256);
    int nodeblocks = (N_NODES + 3) / 4;            // 5000
    const int mt128 = (N_NODES + 127) / 128;       // 157
    const int mt64  = (N_NODES + 63) / 64;         // 313

    // 1. prep: cast x, W^T casts, wa GEMVs, zero deg + als2/ald2
    prep_kernel<<<PB_CASTX + PB_CASTT + PB_WA + PB_ZERO, blk, 0, stream>>>(
        x, xb, W1, w1t, a1s, a1d, W2, w2t, a2s, a2d, W3, w3t, a3s, a3d, wab, deg, alph);
    // 2. count_deg + gemv-L1
    count_gemv1_kernel<<<CB_CNT + nodeblocks, blk, 0, stream>>>(ei, deg, x, wab, als1, ald1);
    // 3. scan
    scan_kernel<<<1, 1024, 0, stream>>>(deg, rowptr, writeptr);
    // 4. fill CSR
    fill_kernel<<<(ET + 255) / 256, blk, 0, stream>>>(ei, writeptr, csr_src);

    // 5. layer-1 aggregation in input space (128 cols)
    agg_kernel<F_IN, false, false, false, true, true, false><<<nodeblocks, blk, 0, stream>>>(
        xb, als1, ald1, rowptr, csr_src, nullptr, zb, nullptr, nullptr, nullptr, nullptr);
    // 6. layer-1 GEMM: y1 = relu(zb @ W1 + b1), fused als2/ald2 epilogue
    gemm_fused<128, 8, true, true, true><<<8 * mt128, blk, 0, stream>>>(
        zb, w1t, y1, b1, N_NODES, F_IN, H1, wab + 256, wab + 768, als2, ald2);
    // 7. layer-2 GEMM: h2 = y1 @ W2
    gemm_fused<128, 4, false, true, false><<<4 * mt128, blk, 0, stream>>>(
        y1, w2t, h2, nullptr, N_NODES, H1, H2, nullptr, nullptr, nullptr, nullptr);
    // 8. layer-2 aggregation: y2 = relu(agg(h2) + b2), fused als3/ald3 epilogue
    agg_kernel<H2, true, true, false, true, true, true><<<nodeblocks, blk, 0, stream>>>(
        h2, als2, ald2, rowptr, csr_src, b2, y2, wab + 1280, wab + 1536, als3, ald3);
    // 9. layer-3 GEMM: h3 = y2 @ W3 (fp32 out)
    gemm_fused<64, 1, false, false, false><<<mt64, blk, 0, stream>>>(
        y2, w3t, h3, nullptr, N_NODES, H2, N_CLS, nullptr, nullptr, nullptr, nullptr);
    // 10. layer-3 aggregation + bias + log_softmax
    agg_kernel<N_CLS, true, false, true, false, false, false><<<nodeblocks, blk, 0, stream>>>(
        h3, als3, ald3, rowptr, csr_src, b3, out, nullptr, nullptr, nullptr, nullptr);
}

// Round 10
// 213.205 us; speedup vs baseline: 4.1983x; 1.2541x over previous
//
#include <hip/hip_runtime.h>
#include <math.h>

#define N_NODES 20000
#define N_EDGESC 320000
#define ET (N_EDGESC + N_NODES)   // 340000 incl. self-loops
#define F_IN 128
#define H1 512
#define H2 256
#define N_CLS 40
#define NEG_SLOPE 0.2f
#define DEGMAX 64                 // slot capacity; overflow list handles deg>64

typedef __attribute__((ext_vector_type(8))) short short8;
typedef __attribute__((ext_vector_type(4))) float floatx4;

__device__ __forceinline__ unsigned short f2bf(float x) {
    unsigned u = __float_as_uint(x);
    unsigned r = (u + 0x7fffu + ((u >> 16) & 1u)) >> 16;  // RNE
    return (unsigned short)r;
}
__device__ __forceinline__ float bflo(unsigned v) { return __uint_as_float(v << 16); }
__device__ __forceinline__ float bfhi(unsigned v) { return __uint_as_float(v & 0xffff0000u); }
__device__ __forceinline__ float leaky(float e) { return (e > 0.f) ? e : e * NEG_SLOPE; }

// ---------------- gemv body: als[i]=in[i,:].wvs, ald[i]=in[i,:].wvd --------
template <int DIN, bool IN_BF16>
__device__ __forceinline__ void gemv2_body(int node, int lane, const void* __restrict__ in,
                                           const float* __restrict__ wvs,
                                           const float* __restrict__ wvd,
                                           float* __restrict__ als, float* __restrict__ ald) {
    constexpr int C = DIN / 64;
    float ss = 0.f, sd = 0.f;
    if constexpr (IN_BF16) {
        const unsigned short* r = (const unsigned short*)in + (size_t)node * DIN + lane * C;
        float f[C];
        if constexpr (C == 8) {
            uint4 v = *(const uint4*)r;
            f[0] = bflo(v.x); f[1] = bfhi(v.x); f[2] = bflo(v.y); f[3] = bfhi(v.y);
            f[4] = bflo(v.z); f[5] = bfhi(v.z); f[6] = bflo(v.w); f[7] = bfhi(v.w);
        } else {
            uint2 v = *(const uint2*)r;
            f[0] = bflo(v.x); f[1] = bfhi(v.x); f[2] = bflo(v.y); f[3] = bfhi(v.y);
        }
        #pragma unroll
        for (int c = 0; c < C; ++c) {
            ss += f[c] * wvs[lane * C + c];
            sd += f[c] * wvd[lane * C + c];
        }
    } else {
        const float* r = (const float*)in + (size_t)node * DIN + lane * 2;
        float2 v = *(const float2*)r;
        ss = v.x * wvs[lane * 2] + v.y * wvs[lane * 2 + 1];
        sd = v.x * wvd[lane * 2] + v.y * wvd[lane * 2 + 1];
    }
    #pragma unroll
    for (int off = 32; off; off >>= 1) {
        ss += __shfl_xor(ss, off);
        sd += __shfl_xor(sd, off);
    }
    if (lane == 0) { als[node] = ss; ald[node] = sd; }
}

// ---------------- prep: cast x, W^T casts, wa GEMVs, zero deg+ocnt ---------
#define NCT (F_IN * H1 + H1 * H2 + H2 * N_CLS)  // 206848
#define PB_CASTX 2500
#define PB_CASTT ((NCT + 255) / 256)             // 808
#define PB_WA 224
#define PB_ZERO ((N_NODES + 1 + 255) / 256)      // deg + ocnt

__global__ __launch_bounds__(256) void prep_kernel(
        const float* __restrict__ x, unsigned short* __restrict__ xb,
        const float* __restrict__ W1, unsigned short* __restrict__ w1t,
        const float* __restrict__ a1s, const float* __restrict__ a1d,
        const float* __restrict__ W2, unsigned short* __restrict__ w2t,
        const float* __restrict__ a2s, const float* __restrict__ a2d,
        const float* __restrict__ W3, unsigned short* __restrict__ w3t,
        const float* __restrict__ a3s, const float* __restrict__ a3d,
        float* __restrict__ wab, int* __restrict__ deg, int* __restrict__ ocnt) {
    int bid = blockIdx.x, t = threadIdx.x;
    if (bid < PB_CASTX) {
        int i = (bid * 256 + t) * 4;
        float4 v = *(const float4*)(x + i);
        ushort4 o = { f2bf(v.x), f2bf(v.y), f2bf(v.z), f2bf(v.w) };
        *(ushort4*)(xb + i) = o;
    } else if (bid < PB_CASTX + PB_CASTT) {
        int i = (bid - PB_CASTX) * 256 + t;
        if (i < F_IN * H1) {
            int k = i >> 9, n = i & 511;
            w1t[n * F_IN + k] = f2bf(W1[i]);
        } else if (i < F_IN * H1 + H1 * H2) {
            int j = i - F_IN * H1;
            int k = j >> 8, n = j & 255;
            w2t[n * H1 + k] = f2bf(W2[j]);
        } else if (i < NCT) {
            int j = i - (F_IN * H1 + H1 * H2);
            int k = j / N_CLS, n = j - k * N_CLS;
            w3t[n * H2 + k] = f2bf(W3[j]);
        }
    } else if (bid < PB_CASTX + PB_CASTT + PB_WA) {
        int lane = t & 63;
        int row = (bid - PB_CASTX - PB_CASTT) * 4 + (t >> 6);  // 0..895
        const float *W, *vs, *vd;
        float *os, *od;
        int N, k;
        if (row < 128)      { k = row;       W = W1; vs = a1s; vd = a1d; os = wab;        od = wab + 128;  N = H1; }
        else if (row < 640) { k = row - 128; W = W2; vs = a2s; vd = a2d; os = wab + 256;  od = wab + 768;  N = H2; }
        else                { k = row - 640; W = W3; vs = a3s; vd = a3d; os = wab + 1280; od = wab + 1536; N = N_CLS; }
        const float* r = W + (size_t)k * N;
        float ss = 0.f, sd = 0.f;
        for (int n = lane; n < N; n += 64) {
            float v = r[n];
            ss += v * vs[n];
            sd += v * vd[n];
        }
        #pragma unroll
        for (int off = 32; off; off >>= 1) {
            ss += __shfl_xor(ss, off);
            sd += __shfl_xor(sd, off);
        }
        if (lane == 0) { os[k] = ss; od[k] = sd; }
    } else {
        int i = (bid - PB_CASTX - PB_CASTT - PB_WA) * 256 + t;
        if (i < N_NODES) deg[i] = 0;
        else if (i == N_NODES) *ocnt = 0;
    }
}

// ---------------- bucket-CSR fill (one pass) + gemv-L1 tail ----------------
#define CB_CNT ((ET + 255) / 256)  // 1329

__global__ __launch_bounds__(256) void fill_gemv1_kernel(
        const int* __restrict__ ei, int* __restrict__ deg,
        int* __restrict__ csr_src, int* __restrict__ ocnt, int* __restrict__ oflow,
        const float* __restrict__ x, const float* __restrict__ wab,
        float* __restrict__ als1, float* __restrict__ ald1) {
    int bid = blockIdx.x, t = threadIdx.x;
    if (bid < CB_CNT) {
        int e = bid * 256 + t;
        if (e < ET) {
            int s, d;
            if (e < N_EDGESC) { s = ei[e]; d = ei[N_EDGESC + e]; }
            else { s = d = e - N_EDGESC; }
            int slot = atomicAdd(&deg[d], 1);
            if (slot < DEGMAX) csr_src[(d << 6) + slot] = s;
            else {
                int o = atomicAdd(ocnt, 1);
                oflow[2 * o] = d;
                oflow[2 * o + 1] = s;
            }
        }
    } else {
        int node = (bid - CB_CNT) * 4 + (t >> 6);
        if (node < N_NODES)
            gemv2_body<F_IN, false>(node, t & 63, x, wab, wab + 128, als1, ald1);
    }
}

// ---------------- softmax-attention aggregation (bucket CSR) ---------------
// ALPHA3: o3s[node]=out_row.wv3s, o3d likewise (fused next-layer alpha dots).
template <int DOUT, bool BIAS, bool RELU, bool LSM, bool IN_BF16, bool OUT_BF16, bool ALPHA3>
__global__ __launch_bounds__(256) void agg_kernel(const void* __restrict__ h,
                                                  const float* __restrict__ as,
                                                  const float* __restrict__ ad,
                                                  const int* __restrict__ deg,
                                                  const int* __restrict__ csr_src,
                                                  const int* __restrict__ ocnt,
                                                  const int* __restrict__ oflow,
                                                  const float* __restrict__ bias,
                                                  void* __restrict__ outp,
                                                  const float* __restrict__ wv3s,
                                                  const float* __restrict__ wv3d,
                                                  float* __restrict__ o3s,
                                                  float* __restrict__ o3d) {
    constexpr int C = (DOUT + 63) / 64;
    int wave = threadIdx.x >> 6, lane = threadIdx.x & 63;
    int node = blockIdx.x * 4 + wave;
    if (node >= N_NODES) return;
    int degt = deg[node];
    int cnt = min(degt, DEGMAX);
    int base = node << 6;
    float adi = ad[node];
    bool ovf = degt > DEGMAX;          // ~never
    int novf = ovf ? *ocnt : 0;

    bool has0 = lane < cnt;
    int sj = has0 ? csr_src[base + lane] : 0;
    float ej = has0 ? leaky(as[sj] + adi) : -INFINITY;

    float m = ej;
    if (ovf) {
        for (int i = lane; i < novf; i += 64)
            if (oflow[2 * i] == node) m = fmaxf(m, leaky(as[oflow[2 * i + 1]] + adi));
    }
    #pragma unroll
    for (int off = 32; off; off >>= 1) m = fmaxf(m, __shfl_xor(m, off));

    float den = has0 ? expf(ej - m) : 0.f;
    if (ovf) {
        for (int i = lane; i < novf; i += 64)
            if (oflow[2 * i] == node) den += expf(leaky(as[oflow[2 * i + 1]] + adi) - m);
    }
    #pragma unroll
    for (int off = 32; off; off >>= 1) den += __shfl_xor(den, off);
    float invden = 1.f / den;

    float wgt = has0 ? expf(ej - m) * invden : 0.f;

    float acc[C];
    #pragma unroll
    for (int c = 0; c < C; ++c) acc[c] = 0.f;

    auto fetch = [&](int s, float* f) {
        if constexpr (IN_BF16) {
            const unsigned short* hr = (const unsigned short*)h + (size_t)s * DOUT + lane * C;
            if constexpr (C == 8) {
                uint4 v = *(const uint4*)hr;
                f[0] = bflo(v.x); f[1] = bfhi(v.x); f[2] = bflo(v.y); f[3] = bfhi(v.y);
                f[4] = bflo(v.z); f[5] = bfhi(v.z); f[6] = bflo(v.w); f[7] = bfhi(v.w);
            } else if constexpr (C == 4) {
                uint2 v = *(const uint2*)hr;
                f[0] = bflo(v.x); f[1] = bfhi(v.x); f[2] = bflo(v.y); f[3] = bfhi(v.y);
            } else {
                unsigned v = *(const unsigned*)hr;
                f[0] = bflo(v); f[1] = bfhi(v);
            }
        } else {
            if (lane < DOUT) f[0] = ((const float*)h)[(size_t)s * DOUT + lane];
            else f[0] = 0.f;
        }
    };

    int j = 0;
    for (; j + 7 < cnt; j += 8) {
        int s[8]; float a[8]; float f[8][C];
        #pragma unroll
        for (int u = 0; u < 8; ++u) { s[u] = __shfl(sj, j + u); a[u] = __shfl(wgt, j + u); }
        #pragma unroll
        for (int u = 0; u < 8; ++u) fetch(s[u], f[u]);
        #pragma unroll
        for (int u = 0; u < 8; ++u)
            #pragma unroll
            for (int c = 0; c < C; ++c) acc[c] += a[u] * f[u][c];
    }
    for (; j < cnt; ++j) {
        int s0 = __shfl(sj, j);
        float a0 = __shfl(wgt, j);
        float f0[C];
        fetch(s0, f0);
        #pragma unroll
        for (int c = 0; c < C; ++c) acc[c] += a0 * f0[c];
    }
    if (ovf) {  // wave-uniform scan of the (tiny) overflow list
        for (int i = 0; i < novf; ++i) {
            if (oflow[2 * i] == node) {
                int s0 = oflow[2 * i + 1];
                float a0 = expf(leaky(as[s0] + adi) - m) * invden;
                float f0[C];
                fetch(s0, f0);
                #pragma unroll
                for (int c = 0; c < C; ++c) acc[c] += a0 * f0[c];
            }
        }
    }

    if constexpr (!LSM) {
        float ps = 0.f, pd = 0.f;
        #pragma unroll
        for (int c = 0; c < C; ++c) {
            int col = lane * C + c;
            if (DOUT % 64 == 0 || col < DOUT) {
                float v = acc[c];
                if constexpr (BIAS) v += bias[col];
                if constexpr (RELU) v = fmaxf(v, 0.f);
                if constexpr (ALPHA3) { ps += v * wv3s[col]; pd += v * wv3d[col]; }
                if constexpr (OUT_BF16)
                    ((unsigned short*)outp)[(size_t)node * DOUT + col] = f2bf(v);
                else
                    ((float*)outp)[(size_t)node * DOUT + col] = v;
            }
        }
        if constexpr (ALPHA3) {
            #pragma unroll
            for (int off = 32; off; off >>= 1) {
                ps += __shfl_xor(ps, off);
                pd += __shfl_xor(pd, off);
            }
            if (lane == 0) { o3s[node] = ps; o3d[node] = pd; }
        }
    } else {
        float v = (lane < DOUT) ? (acc[0] + bias[lane]) : -INFINITY;
        float mm = v;
        #pragma unroll
        for (int off = 32; off; off >>= 1) mm = fmaxf(mm, __shfl_xor(mm, off));
        float ex = (lane < DOUT) ? expf(v - mm) : 0.f;
        float Z = ex;
        #pragma unroll
        for (int off = 32; off; off >>= 1) Z += __shfl_xor(Z, off);
        if (lane < DOUT) ((float*)outp)[(size_t)node * DOUT + lane] = v - mm - logf(Z);
    }
}

// ---------------- MFMA GEMM (1D grid) + optional tail gemv -----------------
#define LDT 40   // padded LDS stride (bf16) per 32-wide k tile
#define LSO 66   // epilogue repack stride (bf16)

template <int MT, int NT, bool BIASRELU, bool OUT_BF16, int GDIN, bool GBF16>
__global__ __launch_bounds__(256) void gemm_fused(
        const unsigned short* __restrict__ A, const unsigned short* __restrict__ Bt,
        void* __restrict__ Cp, const float* __restrict__ bias,
        int M, int K, int N, int gemm_blocks,
        const void* __restrict__ gin, const float* __restrict__ wvs,
        const float* __restrict__ wvd, float* __restrict__ als, float* __restrict__ ald) {
    constexpr int MI = MT / 64;
    __shared__ unsigned short As[MT * LDT];
    __shared__ unsigned short Bs[64 * LDT];
    __shared__ unsigned short Ls[64 * LSO];
    int bid = blockIdx.x, t = threadIdx.x;
    int w = t >> 6, lane = t & 63;

    if (bid >= gemm_blocks) {
        if constexpr (GDIN > 0) {
            int node = (bid - gemm_blocks) * 4 + w;
            if (node < N_NODES)
                gemv2_body<GDIN, GBF16>(node, lane, gin, wvs, wvd, als, ald);
        }
        return;
    }

    int quad = lane >> 4, l16 = lane & 15;
    int bm = (bid / NT) * MT, bn = (bid % NT) * 64;
    int ar0 = t >> 2;
    int ak = (t & 3) * 8;

    floatx4 acc[MI][4];
    #pragma unroll
    for (int i = 0; i < MI; ++i)
        #pragma unroll
        for (int j = 0; j < 4; ++j) acc[i][j] = (floatx4){0.f, 0.f, 0.f, 0.f};

    uint4 pa0 = {0,0,0,0}, pa1 = {0,0,0,0}, pb = {0,0,0,0};
    {
        int gm0 = bm + ar0, gn = bn + ar0;
        if (gm0 < M) pa0 = *(const uint4*)(A + (size_t)gm0 * K + ak);
        if constexpr (MI == 2) {
            int gm1 = bm + 64 + ar0;
            if (gm1 < M) pa1 = *(const uint4*)(A + (size_t)gm1 * K + ak);
        }
        if (gn < N) pb = *(const uint4*)(Bt + (size_t)gn * K + ak);
    }

    for (int k0 = 0; k0 < K; k0 += 32) {
        *(uint4*)(&As[ar0 * LDT + ak]) = pa0;
        if constexpr (MI == 2) *(uint4*)(&As[(64 + ar0) * LDT + ak]) = pa1;
        *(uint4*)(&Bs[ar0 * LDT + ak]) = pb;
        __syncthreads();

        int kn = k0 + 32;
        if (kn < K) {
            int gm0 = bm + ar0, gn = bn + ar0;
            pa0 = (gm0 < M) ? *(const uint4*)(A + (size_t)gm0 * K + kn + ak) : (uint4){0,0,0,0};
            if constexpr (MI == 2) {
                int gm1 = bm + 64 + ar0;
                pa1 = (gm1 < M) ? *(const uint4*)(A + (size_t)gm1 * K + kn + ak) : (uint4){0,0,0,0};
            }
            pb = (gn < N) ? *(const uint4*)(Bt + (size_t)gn * K + kn + ak) : (uint4){0,0,0,0};
        }

        short8 a[MI], b[4];
        #pragma unroll
        for (int mi = 0; mi < MI; ++mi)
            a[mi] = *(short8*)(&As[(w * (MT / 4) + mi * 16 + l16) * LDT + quad * 8]);
        #pragma unroll
        for (int ni = 0; ni < 4; ++ni)
            b[ni] = *(short8*)(&Bs[(ni * 16 + l16) * LDT + quad * 8]);
        #pragma unroll
        for (int mi = 0; mi < MI; ++mi)
            #pragma unroll
            for (int ni = 0; ni < 4; ++ni)
                acc[mi][ni] = __builtin_amdgcn_mfma_f32_16x16x32_bf16(a[mi], b[ni], acc[mi][ni], 0, 0, 0);
        __syncthreads();
    }

    if constexpr (OUT_BF16) {
        #pragma unroll
        for (int mi = 0; mi < MI; ++mi) {
            #pragma unroll
            for (int ni = 0; ni < 4; ++ni) {
                int col = bn + ni * 16 + l16;
                #pragma unroll
                for (int r = 0; r < 4; ++r) {
                    float v = acc[mi][ni][r];
                    if constexpr (BIASRELU) v = fmaxf(v + bias[col], 0.f);
                    Ls[(w * 16 + quad * 4 + r) * LSO + ni * 16 + l16] = f2bf(v);
                }
            }
            __syncthreads();
            #pragma unroll
            for (int i = 0; i < 2; ++i) {
                int idx = t + i * 256;
                int lrow = idx >> 3, c8 = (idx & 7) * 8;
                int grow = bm + (lrow >> 4) * (MT / 4) + mi * 16 + (lrow & 15);
                if (grow < M)
                    *(uint4*)((unsigned short*)Cp + (size_t)grow * N + bn + c8) =
                        *(uint4*)(&Ls[lrow * LSO + c8]);
            }
            __syncthreads();
        }
    } else {
        #pragma unroll
        for (int mi = 0; mi < MI; ++mi) {
            #pragma unroll
            for (int r = 0; r < 4; ++r) {
                int row = bm + w * (MT / 4) + mi * 16 + quad * 4 + r;
                if (row >= M) continue;
                #pragma unroll
                for (int ni = 0; ni < 4; ++ni) {
                    int col = bn + ni * 16 + l16;
                    if (col < N) ((float*)Cp)[(size_t)row * N + col] = acc[mi][ni][r];
                }
            }
        }
    }
}

// ---------------- launch ----------------

extern "C" void kernel_launch(void* const* d_in, const int* in_sizes, int n_in,
                              void* d_out, int out_size, void* d_ws, size_t ws_size,
                              hipStream_t stream) {
    const float* x   = (const float*)d_in[0];
    const int*   ei  = (const int*)d_in[1];
    const float* W1  = (const float*)d_in[2];
    const float* a1s = (const float*)d_in[3];
    const float* a1d = (const float*)d_in[4];
    const float* b1  = (const float*)d_in[5];
    const float* W2  = (const float*)d_in[6];
    const float* a2s = (const float*)d_in[7];
    const float* a2d = (const float*)d_in[8];
    const float* b2  = (const float*)d_in[9];
    const float* W3  = (const float*)d_in[10];
    const float* a3s = (const float*)d_in[11];
    const float* a3d = (const float*)d_in[12];
    const float* b3  = (const float*)d_in[13];
    float* out = (float*)d_out;

    char* ws = (char*)d_ws;
    size_t off = 0;
    auto alloc = [&](size_t bytes) {
        void* p = ws + off;
        off = (off + bytes + 255) & ~(size_t)255;
        return p;
    };
    int*            deg      = (int*)alloc(N_NODES * 4);
    int*            ocnt     = (int*)alloc(4);
    int*            oflow    = (int*)alloc(2 * 8192 * 4);
    int*            csr_src  = (int*)alloc((size_t)N_NODES * DEGMAX * 4);  // 5.1 MB
    float*          alph     = (float*)alloc((size_t)6 * N_NODES * 4);
    float*          wab      = (float*)alloc(1792 * 4);
    unsigned short* xb       = (unsigned short*)alloc((size_t)N_NODES * F_IN * 2);
    unsigned short* w1t      = (unsigned short*)alloc((size_t)H1 * F_IN * 2);
    unsigned short* w2t      = (unsigned short*)alloc((size_t)H2 * H1 * 2);
    unsigned short* w3t      = (unsigned short*)alloc((size_t)N_CLS * H2 * 2);
    unsigned short* zb       = (unsigned short*)alloc((size_t)N_NODES * F_IN * 2);  // agg(x)
    unsigned short* y1       = (unsigned short*)alloc((size_t)N_NODES * H1 * 2);    // L1 out / L2-agg out (aliased)
    unsigned short* h2       = (unsigned short*)alloc((size_t)N_NODES * H2 * 2);
    float*          h3       = (float*)alloc((size_t)N_NODES * N_CLS * 4);
    (void)alloc(128 * 1024);  // slack

    unsigned short* y2 = y1;  // y1 fully consumed before y2 is produced

    float* als1 = alph + 0 * N_NODES; float* ald1 = alph + 1 * N_NODES;
    float* als2 = alph + 2 * N_NODES; float* ald2 = alph + 3 * N_NODES;
    float* als3 = alph + 4 * N_NODES; float* ald3 = alph + 5 * N_NODES;

    dim3 blk(256);
    int nodeblocks = (N_NODES + 3) / 4;            // 5000
    const int mt128 = (N_NODES + 127) / 128;       // 157
    const int mt64  = (N_NODES + 63) / 64;         // 313

    // 1. prep: cast x, W^T casts, wa GEMVs, zero deg/ocnt
    prep_kernel<<<PB_CASTX + PB_CASTT + PB_WA + PB_ZERO, blk, 0, stream>>>(
        x, xb, W1, w1t, a1s, a1d, W2, w2t, a2s, a2d, W3, w3t, a3s, a3d, wab, deg, ocnt);
    // 2. bucket-CSR fill (single pass; no count/scan) + gemv-L1 tail
    fill_gemv1_kernel<<<CB_CNT + nodeblocks, blk, 0, stream>>>(
        ei, deg, csr_src, ocnt, oflow, x, wab, als1, ald1);
    // 3. layer-1 aggregation in input space (128 cols)
    agg_kernel<F_IN, false, false, false, true, true, false><<<nodeblocks, blk, 0, stream>>>(
        xb, als1, ald1, deg, csr_src, ocnt, oflow, nullptr, zb, nullptr, nullptr, nullptr, nullptr);
    // 4. layer-1 GEMM: y1 = relu(zb @ W1 + b1)
    gemm_fused<128, 8, true, true, 0, false><<<8 * mt128, blk, 0, stream>>>(
        zb, w1t, y1, b1, N_NODES, F_IN, H1, 8 * mt128,
        nullptr, nullptr, nullptr, nullptr, nullptr);
    // 5. layer-2 GEMM (h2 = y1 @ W2) + gemv-L2 tail (als2 from y1)
    gemm_fused<128, 4, false, true, H1, true><<<4 * mt128 + nodeblocks, blk, 0, stream>>>(
        y1, w2t, h2, nullptr, N_NODES, H1, H2, 4 * mt128,
        y1, wab + 256, wab + 768, als2, ald2);
    // 6. layer-2 aggregation: y2 = relu(agg(h2) + b2), fused als3/ald3 (atomic-free)
    agg_kernel<H2, true, true, false, true, true, true><<<nodeblocks, blk, 0, stream>>>(
        h2, als2, ald2, deg, csr_src, ocnt, oflow, b2, y2, wab + 1280, wab + 1536, als3, ald3);
    // 7. layer-3 GEMM: h3 = y2 @ W3 (fp32 out)
    gemm_fused<64, 1, false, false, 0, false><<<mt64, blk, 0, stream>>>(
        y2, w3t, h3, nullptr, N_NODES, H2, N_CLS, mt64,
        nullptr, nullptr, nullptr, nullptr, nullptr);
    // 8. layer-3 aggregation + bias + log_softmax
    agg_kernel<N_CLS, true, false, true, false, false, false><<<nodeblocks, blk, 0, stream>>>(
        h3, als3, ald3, deg, csr_src, ocnt, oflow, b3, out, nullptr, nullptr, nullptr, nullptr);
}